// Round 7
// baseline (1436.005 us; speedup 1.0000x reference)
//
#include <hip/hip_runtime.h>

#define NPG 57       // nodes per graph
#define NEPG 160     // edges per graph
#define NB 80        // branches per graph
#define HID 128
#define NG 4096      // graphs
#define NL 5

typedef __attribute__((ext_vector_type(8))) short bf16x8;
typedef __attribute__((ext_vector_type(4))) float f32x4;

__device__ __forceinline__ short f2bf(float f) {
    unsigned u = __builtin_bit_cast(unsigned, f);
    u += 0x7fff + ((u >> 16) & 1);
    return (short)(u >> 16);
}
__device__ __forceinline__ float bf2f(short s) {
    unsigned u = ((unsigned)(unsigned short)s) << 16;
    return __builtin_bit_cast(float, u);
}

// pack two float4 values (BY VALUE — no address-taken arrays, keeps SROA intact)
// into bf16 hi/lo fragments
__device__ __forceinline__ void cvt_pack(float4 a, float4 b, bf16x8& h8, bf16x8& l8) {
#define CVT1(X, I) { short hj = f2bf(X); h8[I] = hj; l8[I] = f2bf((X) - bf2f(hj)); }
    CVT1(a.x, 0) CVT1(a.y, 1) CVT1(a.z, 2) CVT1(a.w, 3)
    CVT1(b.x, 4) CVT1(b.y, 5) CVT1(b.z, 6) CVT1(b.w, 7)
#undef CVT1
}

// build one ks-slice fragment from swizzled LDS row (pure SSA values)
__device__ __forceinline__ void frag_ks(const float (*A)[HID], int row, int kb, int ks,
                                        bf16x8& fh, bf16x8& fl) {
    const int sw = (row & 7) << 2;
    const float* rp = A[row];
    float4 q0 = *(const float4*)&rp[(32 * ks + kb) ^ sw];
    float4 q1 = *(const float4*)&rp[(32 * ks + kb + 4) ^ sw];
    cvt_pack(q0, q1, fh, fl);
}

// one ks-slice of bf16x3 MFMA: frag pair vs B rows [16ct+ln15], col 32ks+kb
template<int NCT>
__device__ __forceinline__ void mm_ks(f32x4* acc, const bf16x8& fh, const bf16x8& fl,
                                      const short* __restrict__ whi,
                                      const short* __restrict__ wlo,
                                      int ln15, int kb, int ks) {
#pragma unroll
    for (int ct = 0; ct < NCT; ++ct) {
        bf16x8 bhi = *(const bf16x8*)(whi + (16 * ct + ln15) * HID + kb + 32 * ks);
        bf16x8 blo = *(const bf16x8*)(wlo + (16 * ct + ln15) * HID + kb + 32 * ks);
        f32x4 a = acc[ct];
        a = __builtin_amdgcn_mfma_f32_16x16x32_bf16(fh, bhi, a, 0, 0, 0);
        a = __builtin_amdgcn_mfma_f32_16x16x32_bf16(fh, blo, a, 0, 0, 0);
        a = __builtin_amdgcn_mfma_f32_16x16x32_bf16(fl, bhi, a, 0, 0, 0);
        acc[ct] = a;
    }
}

// ---- weight prep ----
// wb shorts: [0..229375] conv(5)+P+Q hi/lo pairs (mat*32768 + {0|16384} + n*128+k)
//            [229376..231423] phys hi [16][128]; [231424..233471] phys lo
// fsc/fsh: folded BN scale/shift [5][128] floats
__global__ void prep(const float* __restrict__ convW, const float* __restrict__ mlpW1,
                     const float* __restrict__ physW1, const float* __restrict__ convb,
                     const float* __restrict__ bn_gamma, const float* __restrict__ bn_beta,
                     const float* __restrict__ bn_mean, const float* __restrict__ bn_var,
                     short* __restrict__ wb, float* __restrict__ fsc, float* __restrict__ fsh) {
    int id = blockIdx.x * 256 + threadIdx.x;
    if (id < 114688) {
        int mat = id >> 14, rem = id & 16383, n = rem >> 7, k = rem & 127;
        float w;
        if (mat < 5)       w = convW[mat * 16384 + k * 128 + n];
        else if (mat == 5) w = mlpW1[k * 128 + n];
        else               w = mlpW1[(128 + k) * 128 + n];
        short hi = f2bf(w);
        short lo = f2bf(w - bf2f(hi));
        wb[mat * 32768 + n * 128 + k] = hi;
        wb[mat * 32768 + 16384 + n * 128 + k] = lo;
    } else if (id < 116736) {
        int p = id - 114688, n = p >> 7, k = p & 127;
        float w = physW1[k * 16 + n];
        short hi = f2bf(w);
        short lo = f2bf(w - bf2f(hi));
        wb[229376 + p] = hi;
        wb[231424 + p] = lo;
    } else if (id < 117376) {
        int p = id - 116736;
        float sc = bn_gamma[p] * rsqrtf(bn_var[p] + 1e-5f);
        float sh = fmaf(convb[p] - bn_mean[p], sc, bn_beta[p]);
        fsc[p] = sc;
        fsh[p] = sh;
    }
}

__global__ __launch_bounds__(256, 2) void pinn_fused(
    const float* __restrict__ x, const int* __restrict__ edge_index,
    const int* __restrict__ branch_u, const int* __restrict__ branch_v,
    const float* __restrict__ Wp, const float* __restrict__ bp,
    const float* __restrict__ physb1, const float* __restrict__ physW2,
    const float* __restrict__ physb2,
    const float* __restrict__ mlpW1, const float* __restrict__ mlpb1,
    const float* __restrict__ mlpW2, const float* __restrict__ mlpb2,
    const short* __restrict__ wb, const float* __restrict__ fsc,
    const float* __restrict__ fsh, float* __restrict__ out) {
    __shared__ float h[64][HID];          // 32 KB, XOR-swizzled rows
    __shared__ float dinv[NPG];
    __shared__ int   deg[NPG];
    __shared__ int   rowptr[NPG + 1];
    __shared__ int   cursor[NPG];
    __shared__ short esrc[NEPG], edst[NEPG];
    __shared__ int2  csre[NEPG + NPG];    // edges + self-loops, CSR by dst
    __shared__ float theta[64];
    __shared__ int   bu[NB], bv[NB];

    const int g = blockIdx.x;
    const int tid = threadIdx.x;
    const int lane = tid & 63;
    const int wv = tid >> 6;
    const int ln15 = lane & 15;
    const int hi4 = lane >> 4;
    const int kb = hi4 << 3;            // 0,8,16,24
    const int c = tid & 127;
    const int rg = tid >> 7;
    const int row = 16 * wv + ln15;
    const int r0 = 16 * wv + 4 * hi4;

    // ---- setup: projection + init ----
    {
        float w0 = Wp[c], w1 = Wp[HID + c], w2 = Wp[2 * HID + c], w3 = Wp[3 * HID + c];
        float bb = bp[c];
        for (int r = rg; r < NPG; r += 2) {
            float4 xv = ((const float4*)x)[g * NPG + r];
            h[r][c ^ ((r & 7) << 2)] =
                fmaf(xv.x, w0, fmaf(xv.y, w1, fmaf(xv.z, w2, fmaf(xv.w, w3, bb))));
        }
    }
    if (tid < NPG) deg[tid] = 1;                       // self-loop
    if (tid < NB) { bu[tid] = branch_u[tid]; bv[tid] = branch_v[tid]; }
    for (int i = tid; i < 7 * HID; i += 256) h[57 + (i >> 7)][i & 127] = 0.f;
    __syncthreads();

    if (tid < NEPG) {
        int gs = edge_index[g * NEPG + tid];
        int gd = edge_index[NG * NEPG + g * NEPG + tid];
        short ls = (short)(gs - g * NPG);
        short ld = (short)(gd - g * NPG);
        esrc[tid] = ls;
        edst[tid] = ld;
        atomicAdd(&deg[ld], 1);
    }
    __syncthreads();

    // wave 0: dinv + prefix-scan rowptr + cursor
    if (wv == 0) {
        int dv = (lane < NPG) ? deg[lane] : 0;
        if (lane < NPG) dinv[lane] = rsqrtf((float)dv);
        int val = dv;
#pragma unroll
        for (int o = 1; o < 64; o <<= 1) {
            int t = __shfl_up(val, o, 64);
            if (lane >= o) val += t;
        }
        if (lane < NPG) { rowptr[lane + 1] = val; cursor[lane] = val - dv; }
        if (lane == 0) rowptr[0] = 0;
    }
    __syncthreads();

    if (tid < NEPG) {
        int s = esrc[tid], d = edst[tid];
        int pos = atomicAdd(&cursor[d], 1);
        csre[pos] = make_int2(s, __builtin_bit_cast(int, dinv[s] * dinv[d]));
    }
    if (tid < NPG) {
        int pos = atomicAdd(&cursor[tid], 1);
        csre[pos] = make_int2(tid, __builtin_bit_cast(int, dinv[tid] * dinv[tid]));
    }
    __syncthreads();

    // ---- 5 GCN layers: per-ks {gather-aggregate -> 8ct MFMA} -> BN/ReLU/residual ----
    for (int l = 0; l < NL; ++l) {
        const short* whi = wb + 2 * l * 16384;
        const short* wlo = wb + (2 * l + 1) * 16384;
        const int e0 = (row < NPG) ? rowptr[row] : 0;
        const int e1 = (row < NPG) ? rowptr[row + 1] : 0;

        f32x4 acc[8];
#pragma unroll
        for (int ct = 0; ct < 8; ++ct) acc[ct] = (f32x4){0.f, 0.f, 0.f, 0.f};

#pragma unroll
        for (int ks = 0; ks < 4; ++ks) {
            // gather this ks-slice of the aggregated row into two float4 SSA values
            float4 pa = {0.f, 0.f, 0.f, 0.f};
            float4 qa = {0.f, 0.f, 0.f, 0.f};
            for (int e = e0; e < e1; ++e) {
                int2 ce = csre[e];
                const float* hp = h[ce.x];
                float w = __builtin_bit_cast(float, ce.y);
                const int sw = (ce.x & 7) << 2;
                float4 p0 = *(const float4*)&hp[(32 * ks + kb) ^ sw];
                float4 p1 = *(const float4*)&hp[(32 * ks + kb + 4) ^ sw];
                pa.x = fmaf(w, p0.x, pa.x); pa.y = fmaf(w, p0.y, pa.y);
                pa.z = fmaf(w, p0.z, pa.z); pa.w = fmaf(w, p0.w, pa.w);
                qa.x = fmaf(w, p1.x, qa.x); qa.y = fmaf(w, p1.y, qa.y);
                qa.z = fmaf(w, p1.z, qa.z); qa.w = fmaf(w, p1.w, qa.w);
            }
            bf16x8 fh, fl;
            cvt_pack(pa, qa, fh, fl);
            mm_ks<8>(acc, fh, fl, whi, wlo, ln15, kb, ks);  // frag dies here
        }
        __syncthreads();   // all gathers from h complete before h is rewritten

        const float* sc = fsc + l * HID;
        const float* sh = fsh + l * HID;
#pragma unroll
        for (int ct = 0; ct < 8; ++ct) {
            int ch = 16 * ct + ln15;
            float scv = sc[ch], shv = sh[ch];
#pragma unroll
            for (int q = 0; q < 4; ++q) {
                int rr = r0 + q;
                if (rr < NPG) {
                    float v = fmaf(acc[ct][q], scv, shv);
                    int idx = ch ^ ((rr & 7) << 2);
                    h[rr][idx] = fmaxf(v, 0.f) + h[rr][idx];
                }
            }
        }
        __syncthreads();
    }

    // ---- theta via MFMA (hidden=16), ks-outer ----
    {
        f32x4 t4 = (f32x4){0.f, 0.f, 0.f, 0.f};
#pragma unroll
        for (int ks = 0; ks < 4; ++ks) {
            bf16x8 fh, fl;
            frag_ks(h, row, kb, ks, fh, fl);
            mm_ks<1>(&t4, fh, fl, wb + 229376, wb + 231424, ln15, kb, ks);
        }
        float b1 = physb1[ln15], w2 = physW2[ln15], b2 = physb2[0];
#pragma unroll
        for (int q = 0; q < 4; ++q) {
            float val = fmaxf(t4[q] + b1, 0.f) * w2;
#pragma unroll
            for (int o = 1; o < 16; o <<= 1) val += __shfl_xor(val, o, 16);
            if (ln15 == 0 && r0 + q < NPG) theta[r0 + q] = val + b2;
        }
    }
    __syncthreads();   // theta visible to all

    // ---- branch-direct edge MLP, ks-outer: relu(h[u]@Wp + h[v]@Wq + dth*w256 + b1) @ W2 + b2 ----
    for (int t = wv; t < 5; t += 4) {
        int b = 16 * t + ln15;
        int ru = bu[b], rv = bv[b];
        f32x4 acc[8];
#pragma unroll
        for (int ct = 0; ct < 8; ++ct) acc[ct] = (f32x4){0.f, 0.f, 0.f, 0.f};
#pragma unroll
        for (int ks = 0; ks < 4; ++ks) {
            bf16x8 fh, fl;
            frag_ks(h, ru, kb, ks, fh, fl);
            mm_ks<8>(acc, fh, fl, wb + 10 * 16384, wb + 11 * 16384, ln15, kb, ks);
            frag_ks(h, rv, kb, ks, fh, fl);
            mm_ks<8>(acc, fh, fl, wb + 12 * 16384, wb + 13 * 16384, ln15, kb, ks);
        }

        float dth[4];
#pragma unroll
        for (int q = 0; q < 4; ++q) {
            int bb = 16 * t + 4 * hi4 + q;
            dth[q] = theta[bu[bb]] - theta[bv[bb]];
        }
        float sums[4] = {0.f, 0.f, 0.f, 0.f};
#pragma unroll
        for (int ct = 0; ct < 8; ++ct) {
            int ch = 16 * ct + ln15;
            float w256 = mlpW1[256 * HID + ch];
            float b1 = mlpb1[ch];
            float w2 = mlpW2[ch];
#pragma unroll
            for (int q = 0; q < 4; ++q) {
                float val = fmaxf(fmaf(dth[q], w256, acc[ct][q] + b1), 0.f) * w2;
                sums[q] += val;
            }
        }
        float b2 = mlpb2[0];
#pragma unroll
        for (int q = 0; q < 4; ++q) {
#pragma unroll
            for (int o = 1; o < 16; o <<= 1) sums[q] += __shfl_xor(sums[q], o, 16);
            if (ln15 == 0) out[g * NB + 16 * t + 4 * hi4 + q] = sums[q] + b2;
        }
    }
}

extern "C" void kernel_launch(void* const* d_in, const int* in_sizes, int n_in,
                              void* d_out, int out_size, void* d_ws, size_t ws_size,
                              hipStream_t stream) {
    const float* x          = (const float*)d_in[0];
    const int*   edge_index = (const int*)d_in[1];
    const int*   branch_u   = (const int*)d_in[2];
    const int*   branch_v   = (const int*)d_in[3];
    const float* Wp         = (const float*)d_in[4];
    const float* bp         = (const float*)d_in[5];
    const float* convW      = (const float*)d_in[6];
    const float* convb      = (const float*)d_in[7];
    const float* bn_gamma   = (const float*)d_in[8];
    const float* bn_beta    = (const float*)d_in[9];
    const float* bn_mean    = (const float*)d_in[10];
    const float* bn_var     = (const float*)d_in[11];
    const float* physW1     = (const float*)d_in[12];
    const float* physb1     = (const float*)d_in[13];
    const float* physW2     = (const float*)d_in[14];
    const float* physb2     = (const float*)d_in[15];
    const float* mlpW1      = (const float*)d_in[16];
    const float* mlpb1      = (const float*)d_in[17];
    const float* mlpW2      = (const float*)d_in[18];
    const float* mlpb2      = (const float*)d_in[19];
    float* out = (float*)d_out;

    short* wb = (short*)d_ws;                          // 466944 B
    float* fsc = (float*)((char*)d_ws + 466944);       // 5*128 floats
    float* fsh = fsc + 640;

    prep<<<459, 256, 0, stream>>>(convW, mlpW1, physW1, convb,
                                  bn_gamma, bn_beta, bn_mean, bn_var, wb, fsc, fsh);
    pinn_fused<<<NG, 256, 0, stream>>>(
        x, edge_index, branch_u, branch_v, Wp, bp,
        physb1, physW2, physb2, mlpW1, mlpb1, mlpW2, mlpb2,
        wb, fsc, fsh, out);
}

// Round 8
// 1431.104 us; speedup vs baseline: 1.0034x; 1.0034x over previous
//
#include <hip/hip_runtime.h>

#define NPG 57       // nodes per graph
#define NEPG 160     // edges per graph
#define NB 80        // branches per graph
#define HID 128
#define NG 4096      // graphs
#define NL 5

typedef __attribute__((ext_vector_type(8))) short bf16x8;
typedef __attribute__((ext_vector_type(4))) float f32x4;

__device__ __forceinline__ short f2bf(float f) {
    unsigned u = __builtin_bit_cast(unsigned, f);
    u += 0x7fff + ((u >> 16) & 1);
    return (short)(u >> 16);
}
__device__ __forceinline__ float bf2f(short s) {
    unsigned u = ((unsigned)(unsigned short)s) << 16;
    return __builtin_bit_cast(float, u);
}

// pack two float4 values (by value, SSA-friendly) into bf16 hi/lo fragments
__device__ __forceinline__ void cvt_pack(float4 a, float4 b, bf16x8& h8, bf16x8& l8) {
#define CVT1(X, I) { short hj = f2bf(X); h8[I] = hj; l8[I] = f2bf((X) - bf2f(hj)); }
    CVT1(a.x, 0) CVT1(a.y, 1) CVT1(a.z, 2) CVT1(a.w, 3)
    CVT1(b.x, 4) CVT1(b.y, 5) CVT1(b.z, 6) CVT1(b.w, 7)
#undef CVT1
}

// build one ks-slice fragment from swizzled LDS row (pure SSA values)
__device__ __forceinline__ void frag_ks(const float (*A)[HID], int row, int kb, int ks,
                                        bf16x8& fh, bf16x8& fl) {
    const int sw = (row & 7) << 2;
    const float* rp = A[row];
    float4 q0 = *(const float4*)&rp[(32 * ks + kb) ^ sw];
    float4 q1 = *(const float4*)&rp[(32 * ks + kb + 4) ^ sw];
    cvt_pack(q0, q1, fh, fl);
}

// one ks-slice of bf16x3 MFMA: frag pair vs B rows [16ct+ln15], col 32ks+kb
template<int NCT>
__device__ __forceinline__ void mm_ks(f32x4* acc, const bf16x8& fh, const bf16x8& fl,
                                      const short* __restrict__ whi,
                                      const short* __restrict__ wlo,
                                      int ln15, int kb, int ks) {
#pragma unroll
    for (int ct = 0; ct < NCT; ++ct) {
        bf16x8 bhi = *(const bf16x8*)(whi + (16 * ct + ln15) * HID + kb + 32 * ks);
        bf16x8 blo = *(const bf16x8*)(wlo + (16 * ct + ln15) * HID + kb + 32 * ks);
        f32x4 a = acc[ct];
        a = __builtin_amdgcn_mfma_f32_16x16x32_bf16(fh, bhi, a, 0, 0, 0);
        a = __builtin_amdgcn_mfma_f32_16x16x32_bf16(fh, blo, a, 0, 0, 0);
        a = __builtin_amdgcn_mfma_f32_16x16x32_bf16(fl, bhi, a, 0, 0, 0);
        acc[ct] = a;
    }
}

// ---- weight prep ----
// wb shorts: [0..229375] conv(5)+P+Q hi/lo pairs (mat*32768 + {0|16384} + n*128+k)
//            [229376..231423] phys hi [16][128]; [231424..233471] phys lo
// fsc/fsh: folded BN scale/shift [5][128] floats
__global__ void prep(const float* __restrict__ convW, const float* __restrict__ mlpW1,
                     const float* __restrict__ physW1, const float* __restrict__ convb,
                     const float* __restrict__ bn_gamma, const float* __restrict__ bn_beta,
                     const float* __restrict__ bn_mean, const float* __restrict__ bn_var,
                     short* __restrict__ wb, float* __restrict__ fsc, float* __restrict__ fsh) {
    int id = blockIdx.x * 256 + threadIdx.x;
    if (id < 114688) {
        int mat = id >> 14, rem = id & 16383, n = rem >> 7, k = rem & 127;
        float w;
        if (mat < 5)       w = convW[mat * 16384 + k * 128 + n];
        else if (mat == 5) w = mlpW1[k * 128 + n];
        else               w = mlpW1[(128 + k) * 128 + n];
        short hi = f2bf(w);
        short lo = f2bf(w - bf2f(hi));
        wb[mat * 32768 + n * 128 + k] = hi;
        wb[mat * 32768 + 16384 + n * 128 + k] = lo;
    } else if (id < 116736) {
        int p = id - 114688, n = p >> 7, k = p & 127;
        float w = physW1[k * 16 + n];
        short hi = f2bf(w);
        short lo = f2bf(w - bf2f(hi));
        wb[229376 + p] = hi;
        wb[231424 + p] = lo;
    } else if (id < 117376) {
        int p = id - 116736;
        float sc = bn_gamma[p] * rsqrtf(bn_var[p] + 1e-5f);
        float sh = fmaf(convb[p] - bn_mean[p], sc, bn_beta[p]);
        fsc[p] = sc;
        fsh[p] = sh;
    }
}

// waves_per_eu pinned to [2,2]: launch_bounds(256,2) only sets the MINIMUM —
// with 37KB LDS (4 blocks/CU achievable) the allocator squeezed to exactly 128
// VGPRs chasing 4 waves/EU and spilled ~1.6GB/launch to scratch (R4-R7 evidence:
// VGPR pinned at the 128 occupancy boundary, traffic invariant under 4 different
// codegen structures). Hard max=2 gives a 256-VGPR budget -> no spill.
__global__ __attribute__((amdgpu_flat_work_group_size(256, 256)))
__attribute__((amdgpu_waves_per_eu(2, 2))) void pinn_fused(
    const float* __restrict__ x, const int* __restrict__ edge_index,
    const int* __restrict__ branch_u, const int* __restrict__ branch_v,
    const float* __restrict__ Wp, const float* __restrict__ bp,
    const float* __restrict__ physb1, const float* __restrict__ physW2,
    const float* __restrict__ physb2,
    const float* __restrict__ mlpW1, const float* __restrict__ mlpb1,
    const float* __restrict__ mlpW2, const float* __restrict__ mlpb2,
    const short* __restrict__ wb, const float* __restrict__ fsc,
    const float* __restrict__ fsh, float* __restrict__ out) {
    __shared__ float h[64][HID];          // 32 KB, XOR-swizzled rows
    __shared__ float dinv[NPG];
    __shared__ int   deg[NPG];
    __shared__ int   rowptr[NPG + 1];
    __shared__ int   cursor[NPG];
    __shared__ short esrc[NEPG], edst[NEPG];
    __shared__ int2  csre[NEPG + NPG];    // edges + self-loops, CSR by dst
    __shared__ float theta[64];
    __shared__ int   bu[NB], bv[NB];

    const int g = blockIdx.x;
    const int tid = threadIdx.x;
    const int lane = tid & 63;
    const int wv = tid >> 6;
    const int ln15 = lane & 15;
    const int hi4 = lane >> 4;
    const int kb = hi4 << 3;            // 0,8,16,24
    const int c = tid & 127;
    const int rg = tid >> 7;
    const int row = 16 * wv + ln15;
    const int r0 = 16 * wv + 4 * hi4;

    // ---- setup: projection + init ----
    {
        float w0 = Wp[c], w1 = Wp[HID + c], w2 = Wp[2 * HID + c], w3 = Wp[3 * HID + c];
        float bb = bp[c];
        for (int r = rg; r < NPG; r += 2) {
            float4 xv = ((const float4*)x)[g * NPG + r];
            h[r][c ^ ((r & 7) << 2)] =
                fmaf(xv.x, w0, fmaf(xv.y, w1, fmaf(xv.z, w2, fmaf(xv.w, w3, bb))));
        }
    }
    if (tid < NPG) deg[tid] = 1;                       // self-loop
    if (tid < NB) { bu[tid] = branch_u[tid]; bv[tid] = branch_v[tid]; }
    for (int i = tid; i < 7 * HID; i += 256) h[57 + (i >> 7)][i & 127] = 0.f;
    __syncthreads();

    if (tid < NEPG) {
        int gs = edge_index[g * NEPG + tid];
        int gd = edge_index[NG * NEPG + g * NEPG + tid];
        short ls = (short)(gs - g * NPG);
        short ld = (short)(gd - g * NPG);
        esrc[tid] = ls;
        edst[tid] = ld;
        atomicAdd(&deg[ld], 1);
    }
    __syncthreads();

    // wave 0: dinv + prefix-scan rowptr + cursor
    if (wv == 0) {
        int dv = (lane < NPG) ? deg[lane] : 0;
        if (lane < NPG) dinv[lane] = rsqrtf((float)dv);
        int val = dv;
#pragma unroll
        for (int o = 1; o < 64; o <<= 1) {
            int t = __shfl_up(val, o, 64);
            if (lane >= o) val += t;
        }
        if (lane < NPG) { rowptr[lane + 1] = val; cursor[lane] = val - dv; }
        if (lane == 0) rowptr[0] = 0;
    }
    __syncthreads();

    if (tid < NEPG) {
        int s = esrc[tid], d = edst[tid];
        int pos = atomicAdd(&cursor[d], 1);
        csre[pos] = make_int2(s, __builtin_bit_cast(int, dinv[s] * dinv[d]));
    }
    if (tid < NPG) {
        int pos = atomicAdd(&cursor[tid], 1);
        csre[pos] = make_int2(tid, __builtin_bit_cast(int, dinv[tid] * dinv[tid]));
    }
    __syncthreads();

    // ---- 5 GCN layers: per-ks {gather-aggregate -> 8ct MFMA} -> BN/ReLU/residual ----
    for (int l = 0; l < NL; ++l) {
        const short* whi = wb + 2 * l * 16384;
        const short* wlo = wb + (2 * l + 1) * 16384;
        const int e0 = (row < NPG) ? rowptr[row] : 0;
        const int e1 = (row < NPG) ? rowptr[row + 1] : 0;

        f32x4 acc[8];
#pragma unroll
        for (int ct = 0; ct < 8; ++ct) acc[ct] = (f32x4){0.f, 0.f, 0.f, 0.f};

#pragma unroll
        for (int ks = 0; ks < 4; ++ks) {
            // gather this ks-slice of the aggregated row into two float4 SSA values
            float4 pa = {0.f, 0.f, 0.f, 0.f};
            float4 qa = {0.f, 0.f, 0.f, 0.f};
            for (int e = e0; e < e1; ++e) {
                int2 ce = csre[e];
                const float* hp = h[ce.x];
                float w = __builtin_bit_cast(float, ce.y);
                const int sw = (ce.x & 7) << 2;
                float4 p0 = *(const float4*)&hp[(32 * ks + kb) ^ sw];
                float4 p1 = *(const float4*)&hp[(32 * ks + kb + 4) ^ sw];
                pa.x = fmaf(w, p0.x, pa.x); pa.y = fmaf(w, p0.y, pa.y);
                pa.z = fmaf(w, p0.z, pa.z); pa.w = fmaf(w, p0.w, pa.w);
                qa.x = fmaf(w, p1.x, qa.x); qa.y = fmaf(w, p1.y, qa.y);
                qa.z = fmaf(w, p1.z, qa.z); qa.w = fmaf(w, p1.w, qa.w);
            }
            bf16x8 fh, fl;
            cvt_pack(pa, qa, fh, fl);
            mm_ks<8>(acc, fh, fl, whi, wlo, ln15, kb, ks);  // frag dies here
        }
        __syncthreads();   // all gathers from h complete before h is rewritten

        const float* sc = fsc + l * HID;
        const float* sh = fsh + l * HID;
#pragma unroll
        for (int ct = 0; ct < 8; ++ct) {
            int ch = 16 * ct + ln15;
            float scv = sc[ch], shv = sh[ch];
#pragma unroll
            for (int q = 0; q < 4; ++q) {
                int rr = r0 + q;
                if (rr < NPG) {
                    float v = fmaf(acc[ct][q], scv, shv);
                    int idx = ch ^ ((rr & 7) << 2);
                    h[rr][idx] = fmaxf(v, 0.f) + h[rr][idx];
                }
            }
        }
        __syncthreads();
    }

    // ---- theta via MFMA (hidden=16), ks-outer ----
    {
        f32x4 t4 = (f32x4){0.f, 0.f, 0.f, 0.f};
#pragma unroll
        for (int ks = 0; ks < 4; ++ks) {
            bf16x8 fh, fl;
            frag_ks(h, row, kb, ks, fh, fl);
            mm_ks<1>(&t4, fh, fl, wb + 229376, wb + 231424, ln15, kb, ks);
        }
        float b1 = physb1[ln15], w2 = physW2[ln15], b2 = physb2[0];
#pragma unroll
        for (int q = 0; q < 4; ++q) {
            float val = fmaxf(t4[q] + b1, 0.f) * w2;
#pragma unroll
            for (int o = 1; o < 16; o <<= 1) val += __shfl_xor(val, o, 16);
            if (ln15 == 0 && r0 + q < NPG) theta[r0 + q] = val + b2;
        }
    }
    __syncthreads();   // theta visible to all

    // ---- branch-direct edge MLP, ks-outer: relu(h[u]@Wp + h[v]@Wq + dth*w256 + b1) @ W2 + b2 ----
    for (int t = wv; t < 5; t += 4) {
        int b = 16 * t + ln15;
        int ru = bu[b], rv = bv[b];
        f32x4 acc[8];
#pragma unroll
        for (int ct = 0; ct < 8; ++ct) acc[ct] = (f32x4){0.f, 0.f, 0.f, 0.f};
#pragma unroll
        for (int ks = 0; ks < 4; ++ks) {
            bf16x8 fh, fl;
            frag_ks(h, ru, kb, ks, fh, fl);
            mm_ks<8>(acc, fh, fl, wb + 10 * 16384, wb + 11 * 16384, ln15, kb, ks);
            frag_ks(h, rv, kb, ks, fh, fl);
            mm_ks<8>(acc, fh, fl, wb + 12 * 16384, wb + 13 * 16384, ln15, kb, ks);
        }

        float dth[4];
#pragma unroll
        for (int q = 0; q < 4; ++q) {
            int bb = 16 * t + 4 * hi4 + q;
            dth[q] = theta[bu[bb]] - theta[bv[bb]];
        }
        float sums[4] = {0.f, 0.f, 0.f, 0.f};
#pragma unroll
        for (int ct = 0; ct < 8; ++ct) {
            int ch = 16 * ct + ln15;
            float w256 = mlpW1[256 * HID + ch];
            float b1 = mlpb1[ch];
            float w2 = mlpW2[ch];
#pragma unroll
            for (int q = 0; q < 4; ++q) {
                float val = fmaxf(fmaf(dth[q], w256, acc[ct][q] + b1), 0.f) * w2;
                sums[q] += val;
            }
        }
        float b2 = mlpb2[0];
#pragma unroll
        for (int q = 0; q < 4; ++q) {
#pragma unroll
            for (int o = 1; o < 16; o <<= 1) sums[q] += __shfl_xor(sums[q], o, 16);
            if (ln15 == 0) out[g * NB + 16 * t + 4 * hi4 + q] = sums[q] + b2;
        }
    }
}

extern "C" void kernel_launch(void* const* d_in, const int* in_sizes, int n_in,
                              void* d_out, int out_size, void* d_ws, size_t ws_size,
                              hipStream_t stream) {
    const float* x          = (const float*)d_in[0];
    const int*   edge_index = (const int*)d_in[1];
    const int*   branch_u   = (const int*)d_in[2];
    const int*   branch_v   = (const int*)d_in[3];
    const float* Wp         = (const float*)d_in[4];
    const float* bp         = (const float*)d_in[5];
    const float* convW      = (const float*)d_in[6];
    const float* convb      = (const float*)d_in[7];
    const float* bn_gamma   = (const float*)d_in[8];
    const float* bn_beta    = (const float*)d_in[9];
    const float* bn_mean    = (const float*)d_in[10];
    const float* bn_var     = (const float*)d_in[11];
    const float* physW1     = (const float*)d_in[12];
    const float* physb1     = (const float*)d_in[13];
    const float* physW2     = (const float*)d_in[14];
    const float* physb2     = (const float*)d_in[15];
    const float* mlpW1      = (const float*)d_in[16];
    const float* mlpb1      = (const float*)d_in[17];
    const float* mlpW2      = (const float*)d_in[18];
    const float* mlpb2      = (const float*)d_in[19];
    float* out = (float*)d_out;

    short* wb = (short*)d_ws;                          // 466944 B
    float* fsc = (float*)((char*)d_ws + 466944);       // 5*128 floats
    float* fsh = fsc + 640;

    prep<<<459, 256, 0, stream>>>(convW, mlpW1, physW1, convb,
                                  bn_gamma, bn_beta, bn_mean, bn_var, wb, fsc, fsh);
    pinn_fused<<<NG, 256, 0, stream>>>(
        x, edge_index, branch_u, branch_v, Wp, bp,
        physb1, physW2, physb2, mlpW1, mlpb1, mlpW2, mlpb2,
        wb, fsc, fsh, out);
}

// Round 9
// 1072.753 us; speedup vs baseline: 1.3386x; 1.3340x over previous
//
#include <hip/hip_runtime.h>

#define NPG 57       // nodes per graph
#define NEPG 160     // edges per graph
#define NB 80        // branches per graph
#define HID 128
#define NG 4096      // graphs
#define NL 5

typedef __attribute__((ext_vector_type(8))) short bf16x8;
typedef __attribute__((ext_vector_type(4))) float f32x4;

__device__ __forceinline__ short f2bf(float f) {
    unsigned u = __builtin_bit_cast(unsigned, f);
    u += 0x7fff + ((u >> 16) & 1);
    return (short)(u >> 16);
}
__device__ __forceinline__ float bf2f(short s) {
    unsigned u = ((unsigned)(unsigned short)s) << 16;
    return __builtin_bit_cast(float, u);
}

// pack two float4 values (by value, SSA-friendly) into bf16 hi/lo fragments
__device__ __forceinline__ void cvt_pack(float4 a, float4 b, bf16x8& h8, bf16x8& l8) {
#define CVT1(X, I) { short hj = f2bf(X); h8[I] = hj; l8[I] = f2bf((X) - bf2f(hj)); }
    CVT1(a.x, 0) CVT1(a.y, 1) CVT1(a.z, 2) CVT1(a.w, 3)
    CVT1(b.x, 4) CVT1(b.y, 5) CVT1(b.z, 6) CVT1(b.w, 7)
#undef CVT1
}

// build one ks-slice fragment from swizzled LDS row (pure SSA values)
__device__ __forceinline__ void frag_ks(const float (*A)[HID], int row, int kb, int ks,
                                        bf16x8& fh, bf16x8& fl) {
    const int sw = (row & 7) << 2;
    const float* rp = A[row];
    float4 q0 = *(const float4*)&rp[(32 * ks + kb) ^ sw];
    float4 q1 = *(const float4*)&rp[(32 * ks + kb + 4) ^ sw];
    cvt_pack(q0, q1, fh, fl);
}

// one ks-slice of bf16x3 MFMA over NCT ct-tiles starting at ctbase
template<int NCT>
__device__ __forceinline__ void mm_ks(f32x4* acc, const bf16x8& fh, const bf16x8& fl,
                                      const short* __restrict__ whi,
                                      const short* __restrict__ wlo,
                                      int ln15, int kb, int ks, int ctbase) {
#pragma unroll
    for (int j = 0; j < NCT; ++j) {
        int ct = ctbase + j;
        bf16x8 bhi = *(const bf16x8*)(whi + (16 * ct + ln15) * HID + kb + 32 * ks);
        bf16x8 blo = *(const bf16x8*)(wlo + (16 * ct + ln15) * HID + kb + 32 * ks);
        f32x4 a = acc[j];
        a = __builtin_amdgcn_mfma_f32_16x16x32_bf16(fh, bhi, a, 0, 0, 0);
        a = __builtin_amdgcn_mfma_f32_16x16x32_bf16(fh, blo, a, 0, 0, 0);
        a = __builtin_amdgcn_mfma_f32_16x16x32_bf16(fl, bhi, a, 0, 0, 0);
        acc[j] = a;
    }
}

// ---- weight prep ----
// wb shorts: [0..229375] conv(5)+P+Q hi/lo pairs (mat*32768 + {0|16384} + n*128+k)
//            [229376..231423] phys hi [16][128]; [231424..233471] phys lo
// fsc/fsh: folded BN scale/shift [5][128] floats
__global__ void prep(const float* __restrict__ convW, const float* __restrict__ mlpW1,
                     const float* __restrict__ physW1, const float* __restrict__ convb,
                     const float* __restrict__ bn_gamma, const float* __restrict__ bn_beta,
                     const float* __restrict__ bn_mean, const float* __restrict__ bn_var,
                     short* __restrict__ wb, float* __restrict__ fsc, float* __restrict__ fsh) {
    int id = blockIdx.x * 256 + threadIdx.x;
    if (id < 114688) {
        int mat = id >> 14, rem = id & 16383, n = rem >> 7, k = rem & 127;
        float w;
        if (mat < 5)       w = convW[mat * 16384 + k * 128 + n];
        else if (mat == 5) w = mlpW1[k * 128 + n];
        else               w = mlpW1[(128 + k) * 128 + n];
        short hi = f2bf(w);
        short lo = f2bf(w - bf2f(hi));
        wb[mat * 32768 + n * 128 + k] = hi;
        wb[mat * 32768 + 16384 + n * 128 + k] = lo;
    } else if (id < 116736) {
        int p = id - 114688, n = p >> 7, k = p & 127;
        float w = physW1[k * 16 + n];
        short hi = f2bf(w);
        short lo = f2bf(w - bf2f(hi));
        wb[229376 + p] = hi;
        wb[231424 + p] = lo;
    } else if (id < 117376) {
        int p = id - 116736;
        float sc = bn_gamma[p] * rsqrtf(bn_var[p] + 1e-5f);
        float sh = fmaf(convb[p] - bn_mean[p], sc, bn_beta[p]);
        fsc[p] = sc;
        fsh[p] = sh;
    }
}

// 512 threads (8 waves) per graph. Wave w: rows 16*(w&3)+ln15, ct-half (w>>2)*4..+3.
// Rationale: every prior variant sat at ~7-8 waves/CU (R2 LDS-capped, R4-R8
// scratch-capped) and all landed ~1400us -> latency-bound on occupancy.
// Halving per-wave acc/B-traffic doubles wave count per CU.
__global__ __launch_bounds__(512, 2) void pinn_fused(
    const float* __restrict__ x, const int* __restrict__ edge_index,
    const int* __restrict__ branch_u, const int* __restrict__ branch_v,
    const float* __restrict__ Wp, const float* __restrict__ bp,
    const float* __restrict__ physb1, const float* __restrict__ physW2,
    const float* __restrict__ physb2,
    const float* __restrict__ mlpW1, const float* __restrict__ mlpb1,
    const float* __restrict__ mlpW2, const float* __restrict__ mlpb2,
    const short* __restrict__ wb, const float* __restrict__ fsc,
    const float* __restrict__ fsh, float* __restrict__ out) {
    __shared__ float h[64][HID];          // 32 KB, XOR-swizzled rows
    __shared__ float dinv[NPG];
    __shared__ int   deg[NPG];
    __shared__ int   rowptr[NPG + 1];
    __shared__ int   cursor[NPG];
    __shared__ short esrc[NEPG], edst[NEPG];
    __shared__ int2  csre[NEPG + NPG];    // edges + self-loops, CSR by dst
    __shared__ float theta[64];
    __shared__ float red[NB];
    __shared__ int   bu[NB], bv[NB];

    const int g = blockIdx.x;
    const int tid = threadIdx.x;
    const int lane = tid & 63;
    const int wv = tid >> 6;            // 0..7
    const int ln15 = lane & 15;
    const int hi4 = lane >> 4;
    const int kb = hi4 << 3;            // 0,8,16,24
    const int c = tid & 127;
    const int rg = tid >> 7;            // 0..3
    const int wrow = wv & 3;            // row-tile of this wave
    const int ctbase = (wv >> 2) * 4;   // ct-half of this wave: 0 or 4
    const int row = 16 * wrow + ln15;
    const int r0 = 16 * wrow + 4 * hi4;

    // ---- setup: projection + init ----
    {
        float w0 = Wp[c], w1 = Wp[HID + c], w2 = Wp[2 * HID + c], w3 = Wp[3 * HID + c];
        float bb = bp[c];
        for (int r = rg; r < NPG; r += 4) {
            float4 xv = ((const float4*)x)[g * NPG + r];
            h[r][c ^ ((r & 7) << 2)] =
                fmaf(xv.x, w0, fmaf(xv.y, w1, fmaf(xv.z, w2, fmaf(xv.w, w3, bb))));
        }
    }
    if (tid < NPG) deg[tid] = 1;                       // self-loop
    if (tid < NB) { bu[tid] = branch_u[tid]; bv[tid] = branch_v[tid]; red[tid] = 0.f; }
    for (int i = tid; i < 7 * HID; i += 512) h[57 + (i >> 7)][i & 127] = 0.f;
    __syncthreads();

    if (tid < NEPG) {
        int gs = edge_index[g * NEPG + tid];
        int gd = edge_index[NG * NEPG + g * NEPG + tid];
        short ls = (short)(gs - g * NPG);
        short ld = (short)(gd - g * NPG);
        esrc[tid] = ls;
        edst[tid] = ld;
        atomicAdd(&deg[ld], 1);
    }
    __syncthreads();

    // wave 0: dinv + prefix-scan rowptr + cursor
    if (wv == 0) {
        int dv = (lane < NPG) ? deg[lane] : 0;
        if (lane < NPG) dinv[lane] = rsqrtf((float)dv);
        int val = dv;
#pragma unroll
        for (int o = 1; o < 64; o <<= 1) {
            int t = __shfl_up(val, o, 64);
            if (lane >= o) val += t;
        }
        if (lane < NPG) { rowptr[lane + 1] = val; cursor[lane] = val - dv; }
        if (lane == 0) rowptr[0] = 0;
    }
    __syncthreads();

    if (tid < NEPG) {
        int s = esrc[tid], d = edst[tid];
        int pos = atomicAdd(&cursor[d], 1);
        csre[pos] = make_int2(s, __builtin_bit_cast(int, dinv[s] * dinv[d]));
    }
    if (tid < NPG) {
        int pos = atomicAdd(&cursor[tid], 1);
        csre[pos] = make_int2(tid, __builtin_bit_cast(int, dinv[tid] * dinv[tid]));
    }
    __syncthreads();

    // ---- 5 GCN layers: per-ks {gather-aggregate -> 4ct MFMA} -> BN/ReLU/residual ----
    for (int l = 0; l < NL; ++l) {
        const short* whi = wb + 2 * l * 16384;
        const short* wlo = wb + (2 * l + 1) * 16384;
        const int e0 = (row < NPG) ? rowptr[row] : 0;
        const int e1 = (row < NPG) ? rowptr[row + 1] : 0;

        f32x4 acc[4];
#pragma unroll
        for (int j = 0; j < 4; ++j) acc[j] = (f32x4){0.f, 0.f, 0.f, 0.f};

#pragma unroll
        for (int ks = 0; ks < 4; ++ks) {
            // gather this ks-slice of the aggregated row into two float4 SSA values
            float4 pa = {0.f, 0.f, 0.f, 0.f};
            float4 qa = {0.f, 0.f, 0.f, 0.f};
            for (int e = e0; e < e1; ++e) {
                int2 ce = csre[e];
                const float* hp = h[ce.x];
                float w = __builtin_bit_cast(float, ce.y);
                const int sw = (ce.x & 7) << 2;
                float4 p0 = *(const float4*)&hp[(32 * ks + kb) ^ sw];
                float4 p1 = *(const float4*)&hp[(32 * ks + kb + 4) ^ sw];
                pa.x = fmaf(w, p0.x, pa.x); pa.y = fmaf(w, p0.y, pa.y);
                pa.z = fmaf(w, p0.z, pa.z); pa.w = fmaf(w, p0.w, pa.w);
                qa.x = fmaf(w, p1.x, qa.x); qa.y = fmaf(w, p1.y, qa.y);
                qa.z = fmaf(w, p1.z, qa.z); qa.w = fmaf(w, p1.w, qa.w);
            }
            bf16x8 fh, fl;
            cvt_pack(pa, qa, fh, fl);
            mm_ks<4>(acc, fh, fl, whi, wlo, ln15, kb, ks, ctbase);  // frag dies here
        }
        __syncthreads();   // all gathers from h complete before h is rewritten

        const float* sc = fsc + l * HID;
        const float* sh = fsh + l * HID;
#pragma unroll
        for (int j = 0; j < 4; ++j) {
            int ch = 16 * (ctbase + j) + ln15;
            float scv = sc[ch], shv = sh[ch];
#pragma unroll
            for (int q = 0; q < 4; ++q) {
                int rr = r0 + q;
                if (rr < NPG) {
                    float v = fmaf(acc[j][q], scv, shv);
                    int idx = ch ^ ((rr & 7) << 2);
                    h[rr][idx] = fmaxf(v, 0.f) + h[rr][idx];
                }
            }
        }
        __syncthreads();
    }

    // ---- theta via MFMA (hidden=16), waves 0-3 only ----
    if (wv < 4) {
        f32x4 t4 = (f32x4){0.f, 0.f, 0.f, 0.f};
#pragma unroll
        for (int ks = 0; ks < 4; ++ks) {
            bf16x8 fh, fl;
            frag_ks(h, row, kb, ks, fh, fl);
            mm_ks<1>(&t4, fh, fl, wb + 229376, wb + 231424, ln15, kb, ks, 0);
        }
        float b1 = physb1[ln15], w2 = physW2[ln15], b2 = physb2[0];
#pragma unroll
        for (int q = 0; q < 4; ++q) {
            float val = fmaxf(t4[q] + b1, 0.f) * w2;
#pragma unroll
            for (int o = 1; o < 16; o <<= 1) val += __shfl_xor(val, o, 16);
            if (ln15 == 0 && r0 + q < NPG) theta[r0 + q] = val + b2;
        }
    }
    __syncthreads();   // theta visible to all

    // ---- branch-direct edge MLP, 10 (branch-tile x col-half) tasks over 8 waves ----
    // out[e] = relu(h[u]@Wp + h[v]@Wq + dth*w256 + b1) @ W2 + b2; channel halves
    // combine additively via LDS atomicAdd into red[].
    for (int task = wv; task < 10; task += 8) {
        int t = task >> 1;              // branch tile 0..4
        int cb = (task & 1) * 4;        // ct-half 0 or 4
        int b = 16 * t + ln15;
        int ru = bu[b], rv = bv[b];
        f32x4 acc[4];
#pragma unroll
        for (int j = 0; j < 4; ++j) acc[j] = (f32x4){0.f, 0.f, 0.f, 0.f};
#pragma unroll
        for (int ks = 0; ks < 4; ++ks) {
            bf16x8 fh, fl;
            frag_ks(h, ru, kb, ks, fh, fl);
            mm_ks<4>(acc, fh, fl, wb + 10 * 16384, wb + 11 * 16384, ln15, kb, ks, cb);
            frag_ks(h, rv, kb, ks, fh, fl);
            mm_ks<4>(acc, fh, fl, wb + 12 * 16384, wb + 13 * 16384, ln15, kb, ks, cb);
        }

        float dth[4];
#pragma unroll
        for (int q = 0; q < 4; ++q) {
            int bb = 16 * t + 4 * hi4 + q;
            dth[q] = theta[bu[bb]] - theta[bv[bb]];
        }
        float sums[4] = {0.f, 0.f, 0.f, 0.f};
#pragma unroll
        for (int j = 0; j < 4; ++j) {
            int ch = 16 * (cb + j) + ln15;
            float w256 = mlpW1[256 * HID + ch];
            float b1 = mlpb1[ch];
            float w2 = mlpW2[ch];
#pragma unroll
            for (int q = 0; q < 4; ++q) {
                float val = fmaxf(fmaf(dth[q], w256, acc[j][q] + b1), 0.f) * w2;
                sums[q] += val;
            }
        }
#pragma unroll
        for (int q = 0; q < 4; ++q) {
#pragma unroll
            for (int o = 1; o < 16; o <<= 1) sums[q] += __shfl_xor(sums[q], o, 16);
            if (ln15 == 0) atomicAdd(&red[16 * t + 4 * hi4 + q], sums[q]);
        }
    }
    __syncthreads();
    if (tid < NB) out[g * NB + tid] = red[tid] + mlpb2[0];
}

extern "C" void kernel_launch(void* const* d_in, const int* in_sizes, int n_in,
                              void* d_out, int out_size, void* d_ws, size_t ws_size,
                              hipStream_t stream) {
    const float* x          = (const float*)d_in[0];
    const int*   edge_index = (const int*)d_in[1];
    const int*   branch_u   = (const int*)d_in[2];
    const int*   branch_v   = (const int*)d_in[3];
    const float* Wp         = (const float*)d_in[4];
    const float* bp         = (const float*)d_in[5];
    const float* convW      = (const float*)d_in[6];
    const float* convb      = (const float*)d_in[7];
    const float* bn_gamma   = (const float*)d_in[8];
    const float* bn_beta    = (const float*)d_in[9];
    const float* bn_mean    = (const float*)d_in[10];
    const float* bn_var     = (const float*)d_in[11];
    const float* physW1     = (const float*)d_in[12];
    const float* physb1     = (const float*)d_in[13];
    const float* physW2     = (const float*)d_in[14];
    const float* physb2     = (const float*)d_in[15];
    const float* mlpW1      = (const float*)d_in[16];
    const float* mlpb1      = (const float*)d_in[17];
    const float* mlpW2      = (const float*)d_in[18];
    const float* mlpb2      = (const float*)d_in[19];
    float* out = (float*)d_out;

    short* wb = (short*)d_ws;                          // 466944 B
    float* fsc = (float*)((char*)d_ws + 466944);       // 5*128 floats
    float* fsh = fsc + 640;

    prep<<<459, 256, 0, stream>>>(convW, mlpW1, physW1, convb,
                                  bn_gamma, bn_beta, bn_mean, bn_var, wb, fsc, fsh);
    pinn_fused<<<NG, 512, 0, stream>>>(
        x, edge_index, branch_u, branch_v, Wp, bp,
        physb1, physW2, physb2, mlpW1, mlpb1, mlpW2, mlpb2,
        wb, fsc, fsh, out);
}